// Round 12
// baseline (79.606 us; speedup 1.0000x reference)
//
#include <hip/hip_runtime.h>
#include <math.h>

#define HAND_PARAM_DIM 32
#define INF_DIST 1000000.0f
#define EPS 1e-8f
#define NROW 64        // B*S
#define HW_N 65536
#define NV 778
#define NMESH 1556
#define NMESH_PAD 1568  // 4 quarters * 392
#define QPTS 392
#define K_SEL 1024u
#define HALF_BITS  0x3F000000u  // bits of 0.5f
#define GUESS_BITS 0x3F733333u  // bits of 0.95f (speculative collect threshold)
#define TOP_BITS   0x3F800000u  // bits of 1.0f
#define CHUNK_SLOT 512          // per-(row,chunk) candidate capacity (+21 sigma)
#define CAND_MAX   8192         // 16 * CHUNK_SLOT
#define FIX2 65536.0f           // 2^16 fixed-point scale (packed tail)

// ---- workspace layout (bytes) ----
#define OFF_CAND 0u             // 64*16*512*8 = 4194304
#define OFF_CCNT 4194304u       // 64*16*4     = 4096
#define OFF_CTR  4198400u       // 4 u32: gpack(2), done, spare (8-aligned)
#define OFF_MESH 4198416u       // 64*1568*16  = 1605632 (16-aligned)
#define OFF_SAMP 5804048u       // 64*1024*16  = 1048576

typedef unsigned long long u64;

// ---------------------------------------------------------------------------
// Kernel 1: blocks 0..1023 = speculative collect (one mask pass, NO global
// atomics); blocks 1024..1151 = MANO mesh points. (byte-for-byte the proven
// version). Mesh pre-scaled: m.xyz = -2*p, m.w = |p|^2.
// ---------------------------------------------------------------------------
__global__ void __launch_bounds__(256) combo_kernel(
    const float* __restrict__ mask, const int* __restrict__ hv,
    u64* __restrict__ cand, unsigned* __restrict__ ccnt,
    const float* __restrict__ hp,
    const float* __restrict__ vtl, const float* __restrict__ vtr,
    const float* __restrict__ sdl, const float* __restrict__ sdr,
    const float* __restrict__ pdl, const float* __restrict__ pdr,
    float4* __restrict__ meshP)
{
    int blk = blockIdx.x;
    int t = threadIdx.x;

    if (blk < 1024) {
        __shared__ u64 loc[CHUNK_SLOT];
        __shared__ unsigned nc, nbad;
        int row = blk >> 4, chunk = blk & 15;
        if (!(hv[row*2] | hv[row*2+1])) return;
        if (t == 0) { nc = 0u; nbad = 0u; }
        __syncthreads();
        const float4* m4 = (const float4*)(mask + (size_t)row * HW_N + chunk * 4096);
#pragma unroll
        for (int k = 0; k < 4; k++) {
            float4 v = m4[k*256 + t];
            unsigned e0 = (unsigned)(chunk*4096 + (k*256 + t)*4);
            unsigned u;
#define PROC(comp, off_) { u = __float_as_uint(comp); \
            if (u >= GUESS_BITS) { \
                unsigned p_ = atomicAdd(&nc, 1u); \
                if (p_ < CHUNK_SLOT) loc[p_] = ((u64)u << 32) | (e0 + off_); \
                if (u >= TOP_BITS) nbad = 1u; } }
            PROC(v.x, 0u) PROC(v.y, 1u) PROC(v.z, 2u) PROC(v.w, 3u)
#undef PROC
        }
        __syncthreads();
        unsigned n = (nc < CHUNK_SLOT) ? nc : CHUNK_SLOT;
        if (t == 0) ccnt[row*16 + chunk] = nc | (nbad << 31);
        u64* dst = cand + ((size_t)(row*16 + chunk)) * CHUNK_SLOT;
        for (unsigned i = t; i < n; i += 256) dst[i] = loc[i];
        return;
    }

    // ---- mesh points ----
    int mb   = blk - 1024;
    int row  = mb >> 1;
    int hand = mb & 1;
    const float* p = hp + row * (2 * HAND_PARAM_DIM) + hand * HAND_PARAM_DIM;
    int valid = hv[row * 2 + hand];

    const float* vt = hand ? vtr : vtl;
    const float* sd = hand ? sdr : sdl;
    const float* pd = hand ? pdr : pdl;

    if (hand == 1 && t < (NMESH_PAD - NMESH))
        meshP[row * NMESH_PAD + NMESH + t] = make_float4(0.f, 0.f, 0.f, 3.4e38f);

    float tx = p[0], ty = p[1], tz = p[2];
    float q0 = p[3], q1 = p[4], q2 = p[5], q3 = p[6];
    float qn = sqrtf(q0*q0 + q1*q1 + q2*q2 + q3*q3 + EPS);
    float inv = 1.0f / fmaxf(qn, EPS);
    q0 *= inv; q1 *= inv; q2 *= inv; q3 *= inv;
    float sgn = (q0 < 0.0f) ? -1.0f : 1.0f;
    q0 *= sgn; q1 *= sgn; q2 *= sgn; q3 *= sgn;
    float sin_half = sqrtf(q1*q1 + q2*q2 + q3*q3 + EPS);
    float w_safe = fminf(fmaxf(q0, -1.0f + EPS), 1.0f - EPS);
    float ang2 = 2.0f * atan2f(sin_half, w_safe);
    float factor = (sin_half < 1e-6f) ? 2.0f : ang2 / fmaxf(sin_half, EPS);
    float rx = q1 * factor, ry = q2 * factor, rz = q3 * factor;
    float ang = sqrtf(rx*rx + ry*ry + rz*rz + EPS);
    float iang = 1.0f / ang;
    float ax = rx * iang, ay = ry * iang, az = rz * iang;
    float c = cosf(ang), s = sinf(ang), omc = 1.0f - c;

    float pose[15], betas[10];
#pragma unroll
    for (int k = 0; k < 15; k++) pose[k] = p[7 + k];
#pragma unroll
    for (int k = 0; k < 10; k++) betas[k] = p[22 + k];

    for (int v = t; v < NV; v += 256) {
        float px = vt[v*3+0], py = vt[v*3+1], pz = vt[v*3+2];
        const float* sdv = sd + v * 30;
#pragma unroll
        for (int k = 0; k < 10; k++) {
            px = fmaf(sdv[k],      betas[k], px);
            py = fmaf(sdv[10 + k], betas[k], py);
            pz = fmaf(sdv[20 + k], betas[k], pz);
        }
        const float* pdv = pd + v * 45;
#pragma unroll
        for (int k = 0; k < 15; k++) {
            px = fmaf(pdv[k],      pose[k], px);
            py = fmaf(pdv[15 + k], pose[k], py);
            pz = fmaf(pdv[30 + k], pose[k], pz);
        }
        float cx = ay * pz - az * py;
        float cy = az * px - ax * pz;
        float cz = ax * py - ay * px;
        float kdv = ax * px + ay * py + az * pz;
        float ox = px * c + cx * s + ax * kdv * omc + tx;
        float oy = py * c + cy * s + ay * kdv * omc + ty;
        float oz = pz * c + cz * s + az * kdv * omc + tz;
        if (!valid) { ox = INF_DIST; oy = INF_DIST; oz = INF_DIST; }
        float sb = fmaf(ox, ox, fmaf(oy, oy, oz * oz));
        meshP[row * NMESH_PAD + hand * NV + v] = make_float4(-2.0f*ox, -2.0f*oy, -2.0f*oz, sb);
    }
}

// ---------------------------------------------------------------------------
// Kernel 2: per-row exact top-1024 (byte-for-byte the proven version).
// Fast path: 2-phase radix on (bits - GUESS_BITS); generic 4-phase fallback.
// Emits sampbuf[row][i] = (x,y,z, val>0.5?|s|^2:-1). Block 0 zeroes ctr.
// ---------------------------------------------------------------------------
__global__ void __launch_bounds__(256) sel_fin_kernel(
    const float* __restrict__ mask, const float* __restrict__ means,
    const int* __restrict__ hv,
    const u64* __restrict__ cand, const unsigned* __restrict__ ccnt,
    float4* __restrict__ sampbuf, unsigned* __restrict__ ctr)
{
    __shared__ unsigned cval[CAND_MAX], cidx[CAND_MAX];   // 64 KB
    __shared__ unsigned h[256], seg[256];
    __shared__ unsigned csub[16], cbase[16];
    __shared__ unsigned sbin, sRn, sbad, stot;
    __shared__ unsigned tlist[256];
    __shared__ unsigned tn, ns, scut;
    int row = blockIdx.x, t = threadIdx.x;

    if (row == 0 && t < 4) ctr[t] = 0u;          // gpack lo/hi, done, spare
    for (unsigned i = t; i < K_SEL; i += 256)
        sampbuf[(size_t)row * K_SEL + i] = make_float4(0.f, 0.f, 0.f, -1.0f);
    if (!(hv[row*2] | hv[row*2+1])) return;

    if (t == 0) { sbad = 0u; tn = 0u; ns = 0u; }
    __syncthreads();
    if (t < 16) {
        unsigned w = ccnt[row*16 + t];
        unsigned n = w & 0x7FFFFFFFu;
        csub[t] = (n < CHUNK_SLOT) ? n : CHUNK_SLOT;
        if ((w >> 31) || n > CHUNK_SLOT) atomicOr(&sbad, 1u);
    }
    __syncthreads();
    if (t == 0) {
        unsigned run = 0;
#pragma unroll
        for (int c = 0; c < 16; c++) { cbase[c] = run; run += csub[c]; }
        stot = run;
    }
    __syncthreads();
    unsigned cnt = stot;
    bool ok = (sbad == 0u) && (cnt >= K_SEL) && (cnt <= CAND_MAX);
    const float* mrow = mask + (size_t)row * HW_N;
    unsigned M = ok ? cnt : (unsigned)HW_N;

    if (ok) {
#pragma unroll
        for (int c = 0; c < 16; c++) {
            unsigned n = csub[c], b = cbase[c];
            const u64* src = cand + ((size_t)(row*16 + c)) * CHUNK_SLOT;
            for (unsigned i = t; i < n; i += 256) {
                u64 e = src[i];
                cval[b + i] = (unsigned)(e >> 32); cidx[b + i] = (unsigned)e;
            }
        }
    }
    __syncthreads();

    unsigned T, R;
    if (ok) {
        unsigned pfx = 0u; R = K_SEL;
        for (int ph = 0; ph < 2; ph++) {
            int sh = 8 * (1 - ph);
            h[t] = 0u;
            __syncthreads();
            for (unsigned i = t; i < cnt; i += 256) {
                unsigned off = cval[i] - GUESS_BITS;
                if (ph == 0 || (off >> 8) == pfx) atomicAdd(&h[(off >> sh) & 0xFFu], 1u);
            }
            __syncthreads();
            seg[t] = h[t];
            __syncthreads();
            for (int off2 = 1; off2 < 256; off2 <<= 1) {   // inclusive suffix scan
                unsigned v = (t + off2 < 256) ? seg[t + off2] : 0u;
                __syncthreads(); seg[t] += v; __syncthreads();
            }
            unsigned excl = (t < 255) ? seg[t + 1] : 0u;
            if (excl < R && R <= seg[t]) { sbin = (unsigned)t; sRn = R - excl; }
            __syncthreads();
            pfx = (ph == 0) ? sbin : ((pfx << 8) | sbin);
            R = sRn;
            __syncthreads();
        }
        T = GUESS_BITS + pfx;
    } else {
        unsigned pfx = 0u; R = K_SEL;
        for (int ph = 0; ph < 4; ph++) {
            int sh = 24 - 8 * ph;
            unsigned pm = (ph == 0) ? 0u : (0xFFFFFFFFu << (sh + 8));
            h[t] = 0u;
            __syncthreads();
            for (unsigned i = t; i < M; i += 256) {
                unsigned u = __float_as_uint(mrow[i]);
                if ((u & pm) == pfx) atomicAdd(&h[(u >> sh) & 0xFFu], 1u);
            }
            __syncthreads();
            seg[t] = h[t];
            __syncthreads();
            for (int off2 = 1; off2 < 256; off2 <<= 1) {
                unsigned v = (t + off2 < 256) ? seg[t + off2] : 0u;
                __syncthreads(); seg[t] += v; __syncthreads();
            }
            unsigned excl = (t < 255) ? seg[t + 1] : 0u;
            if (excl < R && R <= seg[t]) { sbin = (unsigned)t; sRn = R - excl; }
            __syncthreads();
            pfx |= sbin << sh;
            R = sRn;
            __syncthreads();
        }
        T = pfx;
    }

    // ---- ties at exact value T -> R-th smallest index is the cut ----
    for (unsigned i = t; i < M; i += 256) {
        unsigned u = ok ? cval[i] : __float_as_uint(mrow[i]);
        if (u == T) {
            unsigned p = atomicAdd(&tn, 1u);
            if (p < 256u) tlist[p] = ok ? cidx[i] : i;
        }
    }
    __syncthreads();
    if (t == 0) {
        unsigned n2 = (tn < 256u) ? tn : 256u;
        for (unsigned a = 1; a < n2; a++) {
            unsigned key = tlist[a]; int b = (int)a - 1;
            while (b >= 0 && tlist[b] > key) { tlist[b+1] = tlist[b]; b--; }
            tlist[b+1] = key;
        }
        unsigned r = R;
        if (r > n2) r = n2;
        if (r < 1u) r = 1u;
        scut = (n2 > 0u) ? tlist[r - 1] : 0u;
    }
    __syncthreads();
    unsigned cut = scut;
    // ---- write the selected set (order-free; downstream sums order-free) ----
    for (unsigned i = t; i < M; i += 256) {
        unsigned u  = ok ? cval[i] : __float_as_uint(mrow[i]);
        unsigned id = ok ? cidx[i] : i;
        if (u > T || (u == T && id <= cut)) {
            unsigned p = atomicAdd(&ns, 1u);
            if (p < K_SEL) {
                const float* gm = means + ((size_t)row * HW_N + id) * 3;
                float sx = gm[0], sy = gm[1], sz = gm[2];
                float sa = fmaf(sx, sx, fmaf(sy, sy, sz * sz));
                float w  = (u > HALF_BITS) ? sa : -1.0f;
                sampbuf[(size_t)row * K_SEL + p] = make_float4(sx, sy, sz, w);
            }
        }
    }
}

// ---------------------------------------------------------------------------
// Kernel 3: self-contained NN distance + packed fence-free atomic tail.
// 1024 blocks = (row XCD-affine, 64-sample chunk); 256 thr = 64 samples x
// 4 mesh-quarters; full 1568-pt mesh in 25KB LDS -> complete min per block.
// Per-block partial packed as (sum*2^16)<<20 | count into ONE u64 atomicAdd
// (integer -> order-invariant -> deterministic). Ticket ordering enforced by
// consuming the atomic return value (vmcnt wait) -- NO __threadfence.
// ---------------------------------------------------------------------------
__global__ void __launch_bounds__(256) dist_kernel(
    const float4* __restrict__ meshP, const float4* __restrict__ sampbuf,
    u64* __restrict__ gpack, unsigned* __restrict__ done,
    float* __restrict__ out)
{
    __shared__ float4 mq[NMESH_PAD];        // 25088 B
    __shared__ float redm[256];
    int blk = blockIdx.x;
    int r = blk & 63, chunk = blk >> 6;     // XCD-affine: row r stays on XCD r%8
    int t = threadIdx.x;
    int s = t & 63, q = t >> 6;

    for (int i = t; i < NMESH_PAD; i += 256) mq[i] = meshP[r * NMESH_PAD + i];

    float4 sp = sampbuf[(size_t)r * K_SEL + chunk * 64 + s];
    float mn = 3.4e38f;
    __syncthreads();

    const int p0 = q * QPTS;
#pragma unroll 4
    for (int i = p0; i < p0 + QPTS; i++) {
        float4 a = mq[i];
        mn = fminf(mn, fmaf(sp.x, a.x, fmaf(sp.y, a.y, fmaf(sp.z, a.z, a.w))));
    }
    redm[t] = mn;
    __syncthreads();

    if (t < 64) {
        float m = fminf(fminf(redm[s], redm[s + 64]),
                        fminf(redm[s + 128], redm[s + 192]));
        u64 pk = 0ull;
        if (sp.w >= 0.0f) {
            float d2 = fmaxf(m + sp.w, 0.0f);
            d2 = fminf(d2, 2000.0f);        // pack-capacity guard (real max ~50)
            pk = ((u64)(d2 * FIX2) << 20) | 1ull;
        }
#pragma unroll
        for (int off = 32; off > 0; off >>= 1)
            pk += __shfl_down(pk, off, 64);
        if (t == 0) {
            u64 oldv = atomicAdd(gpack, pk);
            // consume return value -> s_waitcnt before the ticket issues
            asm volatile("" :: "v"((unsigned)oldv), "v"((unsigned)(oldv >> 32)) : "memory");
            unsigned tk = atomicAdd(done, 1u);
            if (tk == 1023u) {              // all 1024 packed adds completed
                u64 tot = atomicAdd(gpack, 0ull);
                unsigned cc = (unsigned)(tot & 0xFFFFFull);
                double sum = (double)(tot >> 20) / (double)FIX2;
                out[0] = (float)(sum / (double)(cc ? cc : 1u));
            }
        }
    }
}

extern "C" void kernel_launch(void* const* d_in, const int* in_sizes, int n_in,
                              void* d_out, int out_size, void* d_ws, size_t ws_size,
                              hipStream_t stream) {
    const float* hp    = (const float*)d_in[0];
    const float* means = (const float*)d_in[1];
    const float* mask  = (const float*)d_in[2];
    const int*   hv    = (const int*)  d_in[3];
    const float* vtl   = (const float*)d_in[4];
    const float* vtr   = (const float*)d_in[5];
    const float* sdl   = (const float*)d_in[6];
    const float* sdr   = (const float*)d_in[7];
    const float* pdl   = (const float*)d_in[8];
    const float* pdr   = (const float*)d_in[9];
    float* out = (float*)d_out;

    char* ws = (char*)d_ws;
    u64*      cand    = (u64*)(ws + OFF_CAND);
    unsigned* ccnt    = (unsigned*)(ws + OFF_CCNT);
    unsigned* ctr     = (unsigned*)(ws + OFF_CTR);
    float4*   meshP   = (float4*)(ws + OFF_MESH);
    float4*   sampbuf = (float4*)(ws + OFF_SAMP);

    combo_kernel<<<1024 + 128, 256, 0, stream>>>(mask, hv, cand, ccnt,
                                                 hp, vtl, vtr, sdl, sdr, pdl, pdr, meshP);
    sel_fin_kernel<<<NROW, 256, 0, stream>>>(mask, means, hv, cand, ccnt, sampbuf, ctr);
    dist_kernel<<<NROW * 16, 256, 0, stream>>>(meshP, sampbuf,
                                               (u64*)ctr, ctr + 2, out);
}

// Round 13
// 49.829 us; speedup vs baseline: 1.5976x; 1.5976x over previous
//
#include <hip/hip_runtime.h>
#include <math.h>

#define HAND_PARAM_DIM 32
#define INF_DIST 1000000.0f
#define EPS 1e-8f
#define NROW 64        // B*S
#define HW_N 65536
#define NV 778
#define NMESH 1556
#define NMESH_PAD 1568  // 16 slices * 98
#define SLICE 98
#define NSLICE 16
#define K_SEL 1024u
#define HALF_BITS  0x3F000000u  // bits of 0.5f
#define GUESS_BITS 0x3F733333u  // bits of 0.95f (speculative collect threshold)
#define TOP_BITS   0x3F800000u  // bits of 1.0f
#define CHUNK_SLOT 512          // per-(row,chunk) candidate capacity (+21 sigma)
#define CAND_MAX   8192         // 16 * CHUNK_SLOT
#define FIX_SCALE 4294967296.0  // 2^32 fixed-point scale

// ---- workspace layout (bytes) ----
#define OFF_CAND 0u             // 64*16*512*8 = 4194304
#define OFF_CCNT 4194304u       // 64*16*4     = 4096
#define OFF_CTR  4198400u       // 4 u32: gsum(2), gcnt, done (8-aligned)
#define OFF_MESH 4198416u       // 64*1568*16  = 1605632 (16-aligned)
#define OFF_SAMP 5804048u       // 64*1024*16  = 1048576
#define OFF_MINP 6852624u       // 64*16*1024*4 = 4194304

typedef unsigned long long u64;

// ---------------------------------------------------------------------------
// Kernel 1: blocks 0..1023 = speculative collect (one mask pass, NO global
// atomics); blocks 1024..1151 = MANO mesh points. (byte-for-byte the 49.7us
// version). Mesh pre-scaled: m.xyz = -2*p, m.w = |p|^2.
// ---------------------------------------------------------------------------
__global__ void __launch_bounds__(256) combo_kernel(
    const float* __restrict__ mask, const int* __restrict__ hv,
    u64* __restrict__ cand, unsigned* __restrict__ ccnt,
    const float* __restrict__ hp,
    const float* __restrict__ vtl, const float* __restrict__ vtr,
    const float* __restrict__ sdl, const float* __restrict__ sdr,
    const float* __restrict__ pdl, const float* __restrict__ pdr,
    float4* __restrict__ meshP)
{
    int blk = blockIdx.x;
    int t = threadIdx.x;

    if (blk < 1024) {
        __shared__ u64 loc[CHUNK_SLOT];
        __shared__ unsigned nc, nbad;
        int row = blk >> 4, chunk = blk & 15;
        if (!(hv[row*2] | hv[row*2+1])) return;
        if (t == 0) { nc = 0u; nbad = 0u; }
        __syncthreads();
        const float4* m4 = (const float4*)(mask + (size_t)row * HW_N + chunk * 4096);
#pragma unroll
        for (int k = 0; k < 4; k++) {
            float4 v = m4[k*256 + t];
            unsigned e0 = (unsigned)(chunk*4096 + (k*256 + t)*4);
            unsigned u;
#define PROC(comp, off_) { u = __float_as_uint(comp); \
            if (u >= GUESS_BITS) { \
                unsigned p_ = atomicAdd(&nc, 1u); \
                if (p_ < CHUNK_SLOT) loc[p_] = ((u64)u << 32) | (e0 + off_); \
                if (u >= TOP_BITS) nbad = 1u; } }
            PROC(v.x, 0u) PROC(v.y, 1u) PROC(v.z, 2u) PROC(v.w, 3u)
#undef PROC
        }
        __syncthreads();
        unsigned n = (nc < CHUNK_SLOT) ? nc : CHUNK_SLOT;
        if (t == 0) ccnt[row*16 + chunk] = nc | (nbad << 31);
        u64* dst = cand + ((size_t)(row*16 + chunk)) * CHUNK_SLOT;
        for (unsigned i = t; i < n; i += 256) dst[i] = loc[i];
        return;
    }

    // ---- mesh points ----
    int mb   = blk - 1024;
    int row  = mb >> 1;
    int hand = mb & 1;
    const float* p = hp + row * (2 * HAND_PARAM_DIM) + hand * HAND_PARAM_DIM;
    int valid = hv[row * 2 + hand];

    const float* vt = hand ? vtr : vtl;
    const float* sd = hand ? sdr : sdl;
    const float* pd = hand ? pdr : pdl;

    if (hand == 1 && t < (NMESH_PAD - NMESH))
        meshP[row * NMESH_PAD + NMESH + t] = make_float4(0.f, 0.f, 0.f, 3.4e38f);

    float tx = p[0], ty = p[1], tz = p[2];
    float q0 = p[3], q1 = p[4], q2 = p[5], q3 = p[6];
    float qn = sqrtf(q0*q0 + q1*q1 + q2*q2 + q3*q3 + EPS);
    float inv = 1.0f / fmaxf(qn, EPS);
    q0 *= inv; q1 *= inv; q2 *= inv; q3 *= inv;
    float sgn = (q0 < 0.0f) ? -1.0f : 1.0f;
    q0 *= sgn; q1 *= sgn; q2 *= sgn; q3 *= sgn;
    float sin_half = sqrtf(q1*q1 + q2*q2 + q3*q3 + EPS);
    float w_safe = fminf(fmaxf(q0, -1.0f + EPS), 1.0f - EPS);
    float ang2 = 2.0f * atan2f(sin_half, w_safe);
    float factor = (sin_half < 1e-6f) ? 2.0f : ang2 / fmaxf(sin_half, EPS);
    float rx = q1 * factor, ry = q2 * factor, rz = q3 * factor;
    float ang = sqrtf(rx*rx + ry*ry + rz*rz + EPS);
    float iang = 1.0f / ang;
    float ax = rx * iang, ay = ry * iang, az = rz * iang;
    float c = cosf(ang), s = sinf(ang), omc = 1.0f - c;

    float pose[15], betas[10];
#pragma unroll
    for (int k = 0; k < 15; k++) pose[k] = p[7 + k];
#pragma unroll
    for (int k = 0; k < 10; k++) betas[k] = p[22 + k];

    for (int v = t; v < NV; v += 256) {
        float px = vt[v*3+0], py = vt[v*3+1], pz = vt[v*3+2];
        const float* sdv = sd + v * 30;
#pragma unroll
        for (int k = 0; k < 10; k++) {
            px = fmaf(sdv[k],      betas[k], px);
            py = fmaf(sdv[10 + k], betas[k], py);
            pz = fmaf(sdv[20 + k], betas[k], pz);
        }
        const float* pdv = pd + v * 45;
#pragma unroll
        for (int k = 0; k < 15; k++) {
            px = fmaf(pdv[k],      pose[k], px);
            py = fmaf(pdv[15 + k], pose[k], py);
            pz = fmaf(pdv[30 + k], pose[k], pz);
        }
        float cx = ay * pz - az * py;
        float cy = az * px - ax * pz;
        float cz = ax * py - ay * px;
        float kdv = ax * px + ay * py + az * pz;
        float ox = px * c + cx * s + ax * kdv * omc + tx;
        float oy = py * c + cy * s + ay * kdv * omc + ty;
        float oz = pz * c + cz * s + az * kdv * omc + tz;
        if (!valid) { ox = INF_DIST; oy = INF_DIST; oz = INF_DIST; }
        float sb = fmaf(ox, ox, fmaf(oy, oy, oz * oz));
        meshP[row * NMESH_PAD + hand * NV + v] = make_float4(-2.0f*ox, -2.0f*oy, -2.0f*oz, sb);
    }
}

// ---------------------------------------------------------------------------
// Kernel 2: per-row exact top-1024 (byte-for-byte the 49.7us version).
// Fast path: 2-phase radix on (bits - GUESS_BITS); generic 4-phase fallback.
// Emits sampbuf[row][i] = (x,y,z, val>0.5?|s|^2:-1). Block 0 zeroes ctr.
// ---------------------------------------------------------------------------
__global__ void __launch_bounds__(256) sel_fin_kernel(
    const float* __restrict__ mask, const float* __restrict__ means,
    const int* __restrict__ hv,
    const u64* __restrict__ cand, const unsigned* __restrict__ ccnt,
    float4* __restrict__ sampbuf, unsigned* __restrict__ ctr)
{
    __shared__ unsigned cval[CAND_MAX], cidx[CAND_MAX];   // 64 KB
    __shared__ unsigned h[256], seg[256];
    __shared__ unsigned csub[16], cbase[16];
    __shared__ unsigned sbin, sRn, sbad, stot;
    __shared__ unsigned tlist[256];
    __shared__ unsigned tn, ns, scut;
    int row = blockIdx.x, t = threadIdx.x;

    if (row == 0 && t < 4) ctr[t] = 0u;          // gsum lo/hi, gcnt, done
    for (unsigned i = t; i < K_SEL; i += 256)
        sampbuf[(size_t)row * K_SEL + i] = make_float4(0.f, 0.f, 0.f, -1.0f);
    if (!(hv[row*2] | hv[row*2+1])) return;

    if (t == 0) { sbad = 0u; tn = 0u; ns = 0u; }
    __syncthreads();
    if (t < 16) {
        unsigned w = ccnt[row*16 + t];
        unsigned n = w & 0x7FFFFFFFu;
        csub[t] = (n < CHUNK_SLOT) ? n : CHUNK_SLOT;
        if ((w >> 31) || n > CHUNK_SLOT) atomicOr(&sbad, 1u);
    }
    __syncthreads();
    if (t == 0) {
        unsigned run = 0;
#pragma unroll
        for (int c = 0; c < 16; c++) { cbase[c] = run; run += csub[c]; }
        stot = run;
    }
    __syncthreads();
    unsigned cnt = stot;
    bool ok = (sbad == 0u) && (cnt >= K_SEL) && (cnt <= CAND_MAX);
    const float* mrow = mask + (size_t)row * HW_N;
    unsigned M = ok ? cnt : (unsigned)HW_N;

    if (ok) {
#pragma unroll
        for (int c = 0; c < 16; c++) {
            unsigned n = csub[c], b = cbase[c];
            const u64* src = cand + ((size_t)(row*16 + c)) * CHUNK_SLOT;
            for (unsigned i = t; i < n; i += 256) {
                u64 e = src[i];
                cval[b + i] = (unsigned)(e >> 32); cidx[b + i] = (unsigned)e;
            }
        }
    }
    __syncthreads();

    unsigned T, R;
    if (ok) {
        unsigned pfx = 0u; R = K_SEL;
        for (int ph = 0; ph < 2; ph++) {
            int sh = 8 * (1 - ph);
            h[t] = 0u;
            __syncthreads();
            for (unsigned i = t; i < cnt; i += 256) {
                unsigned off = cval[i] - GUESS_BITS;
                if (ph == 0 || (off >> 8) == pfx) atomicAdd(&h[(off >> sh) & 0xFFu], 1u);
            }
            __syncthreads();
            seg[t] = h[t];
            __syncthreads();
            for (int off2 = 1; off2 < 256; off2 <<= 1) {   // inclusive suffix scan
                unsigned v = (t + off2 < 256) ? seg[t + off2] : 0u;
                __syncthreads(); seg[t] += v; __syncthreads();
            }
            unsigned excl = (t < 255) ? seg[t + 1] : 0u;
            if (excl < R && R <= seg[t]) { sbin = (unsigned)t; sRn = R - excl; }
            __syncthreads();
            pfx = (ph == 0) ? sbin : ((pfx << 8) | sbin);
            R = sRn;
            __syncthreads();
        }
        T = GUESS_BITS + pfx;
    } else {
        unsigned pfx = 0u; R = K_SEL;
        for (int ph = 0; ph < 4; ph++) {
            int sh = 24 - 8 * ph;
            unsigned pm = (ph == 0) ? 0u : (0xFFFFFFFFu << (sh + 8));
            h[t] = 0u;
            __syncthreads();
            for (unsigned i = t; i < M; i += 256) {
                unsigned u = __float_as_uint(mrow[i]);
                if ((u & pm) == pfx) atomicAdd(&h[(u >> sh) & 0xFFu], 1u);
            }
            __syncthreads();
            seg[t] = h[t];
            __syncthreads();
            for (int off2 = 1; off2 < 256; off2 <<= 1) {
                unsigned v = (t + off2 < 256) ? seg[t + off2] : 0u;
                __syncthreads(); seg[t] += v; __syncthreads();
            }
            unsigned excl = (t < 255) ? seg[t + 1] : 0u;
            if (excl < R && R <= seg[t]) { sbin = (unsigned)t; sRn = R - excl; }
            __syncthreads();
            pfx |= sbin << sh;
            R = sRn;
            __syncthreads();
        }
        T = pfx;
    }

    // ---- ties at exact value T -> R-th smallest index is the cut ----
    for (unsigned i = t; i < M; i += 256) {
        unsigned u = ok ? cval[i] : __float_as_uint(mrow[i]);
        if (u == T) {
            unsigned p = atomicAdd(&tn, 1u);
            if (p < 256u) tlist[p] = ok ? cidx[i] : i;
        }
    }
    __syncthreads();
    if (t == 0) {
        unsigned n2 = (tn < 256u) ? tn : 256u;
        for (unsigned a = 1; a < n2; a++) {
            unsigned key = tlist[a]; int b = (int)a - 1;
            while (b >= 0 && tlist[b] > key) { tlist[b+1] = tlist[b]; b--; }
            tlist[b+1] = key;
        }
        unsigned r = R;
        if (r > n2) r = n2;
        if (r < 1u) r = 1u;
        scut = (n2 > 0u) ? tlist[r - 1] : 0u;
    }
    __syncthreads();
    unsigned cut = scut;
    // ---- write the selected set (order-free; downstream sums order-free) ----
    for (unsigned i = t; i < M; i += 256) {
        unsigned u  = ok ? cval[i] : __float_as_uint(mrow[i]);
        unsigned id = ok ? cidx[i] : i;
        if (u > T || (u == T && id <= cut)) {
            unsigned p = atomicAdd(&ns, 1u);
            if (p < K_SEL) {
                const float* gm = means + ((size_t)row * HW_N + id) * 3;
                float sx = gm[0], sy = gm[1], sz = gm[2];
                float sa = fmaf(sx, sx, fmaf(sy, sy, sz * sz));
                float w  = (u > HALF_BITS) ? sa : -1.0f;
                sampbuf[(size_t)row * K_SEL + p] = make_float4(sx, sy, sz, w);
            }
        }
    }
}

// ---------------------------------------------------------------------------
// Kernel 3: NN partial mins. 1024 blocks, XCD-affine: blk = sl*64 + row so
// all 16 slice-blocks of row r land on XCD r%8 (64%8==0) -> minpart/sampbuf
// row stays in one L2. 256 threads, 4 samples/lane (16 waves/CU), 4
// independent min accumulators. No atomics, no fences.
// ---------------------------------------------------------------------------
__global__ void __launch_bounds__(256) dist_kernel(
    const float4* __restrict__ meshP, const float4* __restrict__ sampbuf,
    float* __restrict__ minpart)
{
    __shared__ float4 mq[SLICE];
    int blk = blockIdx.x;
    int r = blk & 63, sl = blk >> 6;          // XCD-affine mapping
    int t = threadIdx.x;

    if (t < SLICE) mq[t] = meshP[r * NMESH_PAD + sl * SLICE + t];

    const float4* sb = sampbuf + (size_t)r * K_SEL;
    float sx[4], sy[4], sz[4], mn[4];
#pragma unroll
    for (int k = 0; k < 4; k++) {
        float4 s = sb[t + 256*k];
        sx[k] = s.x; sy[k] = s.y; sz[k] = s.z;
        mn[k] = 3.4e38f;
    }
    __syncthreads();

#pragma unroll 2
    for (int i = 0; i < SLICE; i++) {
        float4 a = mq[i];
#pragma unroll
        for (int k = 0; k < 4; k++)
            mn[k] = fminf(mn[k], fmaf(sx[k], a.x, fmaf(sy[k], a.y, fmaf(sz[k], a.z, a.w))));
    }

    float* mp = minpart + ((size_t)r * NSLICE + sl) * K_SEL;
#pragma unroll
    for (int k = 0; k < 4; k++) mp[t + 256*k] = mn[k];
}

// ---------------------------------------------------------------------------
// Kernel 4: per-sample min over 16 slices + per-row fixed-point sum +
// last-of-64 ticket finalize (64 fences total -- proven cheap). Block r reads
// its row's minpart from the same XCD L2 (r%8). Integer adds -> deterministic.
// ---------------------------------------------------------------------------
__global__ void __launch_bounds__(256) reduce_kernel(
    const float* __restrict__ minpart, const float4* __restrict__ sampbuf,
    unsigned* __restrict__ ctr, float* __restrict__ out)
{
    __shared__ long long rs[256];
    __shared__ unsigned rc[256];
    int row = blockIdx.x;
    int t = threadIdx.x;

    long long acc = 0; unsigned c = 0;
#pragma unroll
    for (int k = 0; k < 4; k++) {
        int j = k * 256 + t;
        const float* mp = minpart + (size_t)row * NSLICE * K_SEL + j;
        float m = mp[0];
#pragma unroll
        for (int s = 1; s < NSLICE; s++) m = fminf(m, mp[s * (int)K_SEL]);
        float4 sp = sampbuf[(size_t)row * K_SEL + j];
        if (sp.w >= 0.0f) {
            float d2 = fmaxf(m + sp.w, 0.0f);
            acc += (long long)((double)d2 * FIX_SCALE);
            c += 1u;
        }
    }
    rs[t] = acc; rc[t] = c;
    __syncthreads();
    for (int off = 128; off > 0; off >>= 1) {
        if (t < off) { rs[t] += rs[t+off]; rc[t] += rc[t+off]; }
        __syncthreads();
    }
    if (t == 0) {
        atomicAdd((u64*)ctr, (u64)rs[0]);
        atomicAdd(&ctr[2], rc[0]);
        __threadfence();
        unsigned tk = atomicAdd(&ctr[3], 1u);
        if (tk == (unsigned)(NROW - 1)) {
            u64 sbits = atomicAdd((u64*)ctr, 0ull);
            unsigned cc = atomicAdd(&ctr[2], 0u);
            double sum = (double)(long long)sbits / FIX_SCALE;
            out[0] = (float)(sum / (double)(cc ? cc : 1u));
        }
    }
}

extern "C" void kernel_launch(void* const* d_in, const int* in_sizes, int n_in,
                              void* d_out, int out_size, void* d_ws, size_t ws_size,
                              hipStream_t stream) {
    const float* hp    = (const float*)d_in[0];
    const float* means = (const float*)d_in[1];
    const float* mask  = (const float*)d_in[2];
    const int*   hv    = (const int*)  d_in[3];
    const float* vtl   = (const float*)d_in[4];
    const float* vtr   = (const float*)d_in[5];
    const float* sdl   = (const float*)d_in[6];
    const float* sdr   = (const float*)d_in[7];
    const float* pdl   = (const float*)d_in[8];
    const float* pdr   = (const float*)d_in[9];
    float* out = (float*)d_out;

    char* ws = (char*)d_ws;
    u64*      cand    = (u64*)(ws + OFF_CAND);
    unsigned* ccnt    = (unsigned*)(ws + OFF_CCNT);
    unsigned* ctr     = (unsigned*)(ws + OFF_CTR);
    float4*   meshP   = (float4*)(ws + OFF_MESH);
    float4*   sampbuf = (float4*)(ws + OFF_SAMP);
    float*    minpart = (float*)(ws + OFF_MINP);

    combo_kernel<<<1024 + 128, 256, 0, stream>>>(mask, hv, cand, ccnt,
                                                 hp, vtl, vtr, sdl, sdr, pdl, pdr, meshP);
    sel_fin_kernel<<<NROW, 256, 0, stream>>>(mask, means, hv, cand, ccnt, sampbuf, ctr);
    dist_kernel<<<NROW * NSLICE, 256, 0, stream>>>(meshP, sampbuf, minpart);
    reduce_kernel<<<NROW, 256, 0, stream>>>(minpart, sampbuf, ctr, out);
}